// Round 2
// baseline (102.303 us; speedup 1.0000x reference)
//
#include <hip/hip_runtime.h>
#include <math.h>

#define NPTS    18
#define NDIMS   4
#define NITER   15   // num_splines - 1
#define RSTRIDE 28   // floats per table row: 24 used + 4 pad (112 B; random rows spread banks, <=2-way)
#define NBLK    2048

__device__ __forceinline__ float sigm(float v) { return 1.0f / (1.0f + expf(-v)); }

// ---------------- Kernel P: full prep in ONE block ----------------
// MLP for all 18 points (layer-parallel), cumsum, 15-step recurrence -> table in d_ws.
__global__ __launch_bounds__(256) void prep_kernel(
    const float* __restrict__ W1, const float* __restrict__ b1,
    const float* __restrict__ W2, const float* __restrict__ b2,
    const float* __restrict__ W3, const float* __restrict__ b3,
    const float* __restrict__ W4, const float* __restrict__ b4,
    const float* __restrict__ W5, const float* __restrict__ b5,
    const float* __restrict__ W6, const float* __restrict__ b6,
    float* __restrict__ tbl)
{
    __shared__ float h1[NPTS * 16];
    __shared__ float h2[NPTS * 64];
    __shared__ float h3[NPTS * 256];
    __shared__ float h4[NPTS * 64];
    __shared__ float h5[NPTS * 16];
    __shared__ float z6[NPTS * NDIMS];
    __shared__ float Pl[NPTS * NDIMS];
    const int t = threadIdx.x;

    // L1: (1 -> 16) sigmoid, 288 outputs
    for (int idx = t; idx < NPTS * 16; idx += 256) {
        int p = idx >> 4, o = idx & 15;
        h1[idx] = sigm(fmaf(W1[o], (float)(p + 1), b1[o]));
    }
    __syncthreads();

    // L2: (16 -> 64) sigmoid, 1152 outputs
    for (int idx = t; idx < NPTS * 64; idx += 256) {
        int p = idx >> 6, o = idx & 63;
        float a = b2[o];
        #pragma unroll
        for (int i = 0; i < 16; ++i) a = fmaf(W2[o * 16 + i], h1[p * 16 + i], a);
        h2[idx] = sigm(a);
    }
    __syncthreads();

    // L3: (64 -> 256) relu, 4608 outputs
    for (int idx = t; idx < NPTS * 256; idx += 256) {
        int p = idx >> 8, o = idx & 255;
        const float* w = W3 + o * 64;
        const float* hh = h2 + p * 64;
        float a0 = 0.f, a1 = 0.f, a2 = 0.f, a3 = 0.f;
        #pragma unroll 4
        for (int i = 0; i < 64; i += 4) {
            a0 = fmaf(w[i + 0], hh[i + 0], a0);
            a1 = fmaf(w[i + 1], hh[i + 1], a1);
            a2 = fmaf(w[i + 2], hh[i + 2], a2);
            a3 = fmaf(w[i + 3], hh[i + 3], a3);
        }
        h3[idx] = fmaxf(b3[o] + ((a0 + a1) + (a2 + a3)), 0.f);
    }
    __syncthreads();

    // L4: (256 -> 64) relu, 1152 outputs
    for (int idx = t; idx < NPTS * 64; idx += 256) {
        int p = idx >> 6, o = idx & 63;
        const float* w = W4 + o * 256;
        const float* hh = h3 + p * 256;
        float a0 = 0.f, a1 = 0.f, a2 = 0.f, a3 = 0.f;
        #pragma unroll 4
        for (int i = 0; i < 256; i += 4) {
            a0 = fmaf(w[i + 0], hh[i + 0], a0);
            a1 = fmaf(w[i + 1], hh[i + 1], a1);
            a2 = fmaf(w[i + 2], hh[i + 2], a2);
            a3 = fmaf(w[i + 3], hh[i + 3], a3);
        }
        h4[idx] = fmaxf(b4[o] + ((a0 + a1) + (a2 + a3)), 0.f);
    }
    __syncthreads();

    // L5: (64 -> 16) relu, 288 outputs
    for (int idx = t; idx < NPTS * 16; idx += 256) {
        int p = idx >> 4, o = idx & 15;
        const float* w = W5 + o * 64;
        const float* hh = h4 + p * 64;
        float a0 = 0.f, a1 = 0.f, a2 = 0.f, a3 = 0.f;
        #pragma unroll 4
        for (int i = 0; i < 64; i += 4) {
            a0 = fmaf(w[i + 0], hh[i + 0], a0);
            a1 = fmaf(w[i + 1], hh[i + 1], a1);
            a2 = fmaf(w[i + 2], hh[i + 2], a2);
            a3 = fmaf(w[i + 3], hh[i + 3], a3);
        }
        h5[idx] = fmaxf(b5[o] + ((a0 + a1) + (a2 + a3)), 0.f);
    }
    __syncthreads();

    // L6: (16 -> 4), 72 outputs
    if (t < NPTS * NDIMS) {
        int p = t >> 2, j = t & 3;
        float a = b6[j];
        #pragma unroll
        for (int i = 0; i < 16; ++i) a = fmaf(W6[j * 16 + i], h5[p * 16 + i], a);
        z6[t] = a;
    }
    __syncthreads();

    // cumsum over dims within each point
    if (t < NPTS) {
        float c = 0.f;
        #pragma unroll
        for (int j = 0; j < NDIMS; ++j) {
            c += z6[t * NDIMS + j];
            Pl[t * NDIMS + j] = c;
        }
    }
    __syncthreads();

    // 15-step control-point recurrence -> global table
    // row i: [Pt0(4) Pt1(4) Pt2(4) Pn0(4) Pn1(4) Pn2(4) pad(4)]
    if (t < NDIMS) {
        const int j = t;
        float P0 = Pl[0 * NDIMS + j];
        float P1 = Pl[1 * NDIMS + j];
        float P2 = Pl[2 * NDIMS + j];
        for (int i = 0; i < NITER; ++i) {
            float Pnext = Pl[(3 + i) * NDIMS + j];
            float p0 = (P0 + P2) * 0.25f + P1 * 0.5f;
            float p2 = Pnext;
            float p1 = 2.0f * (P2 - (p0 + p2) * 0.25f);
            float* row = tbl + i * RSTRIDE;
            row[0 * 4 + j] = P0; row[1 * 4 + j] = P1; row[2 * 4 + j] = P2;
            row[3 * 4 + j] = p0; row[4 * 4 + j] = p1; row[5 * 4 + j] = p2;
            P0 = p0; P1 = p1; P2 = p2;
        }
    }
}

// ---------------- Kernel B: per-element spline evaluation ----------------
__global__ __launch_bounds__(256) void spline_kernel(
    const float* __restrict__ x, const float* __restrict__ tbl,
    float4* __restrict__ out4, int n)
{
    __shared__ float s[NITER * RSTRIDE];
    for (int k = threadIdx.x; k < NITER * RSTRIDE; k += 256) s[k] = tbl[k];
    __syncthreads();

    const int stride = NBLK * 256;
    for (int i = blockIdx.x * 256 + threadIdx.x; i < n; i += stride) {
        float u  = x[i] * 15.0f;
        float fi = floorf(u);
        fi = fminf(fmaxf(fi, 0.0f), 14.0f);   // last matching choice == floor bucket
        float d  = (u - fi) * 0.5f;           // in [0, 0.5)

        const float* row = s + (int)fi * RSTRIDE;
        float4 Pt0 = *(const float4*)(row + 0);
        float4 Pt1 = *(const float4*)(row + 4);
        float4 Pt2 = *(const float4*)(row + 8);
        float4 Pn0 = *(const float4*)(row + 12);
        float4 Pn1 = *(const float4*)(row + 16);
        float4 Pn2 = *(const float4*)(row + 20);

        // Bernstein bases: prev at (d+0.5), curr at d
        float dp  = d + 0.5f, omp = 0.5f - d;
        float cp0 = omp * omp, cp1 = 2.0f * dp * omp, cp2 = dp * dp;
        float omd = 1.0f - d;
        float cc0 = omd * omd, cc1 = 2.0f * d * omd, cc2 = d * d;

        // wc = cos^2(pi d) = 0.5 + 0.5*cos(2 pi d); ws = 1 - wc (exact identity)
        float wc = fmaf(0.5f, cospif(2.0f * d), 0.5f);

        float4 r;
        {
            float fp = fmaf(cp0, Pt0.x, fmaf(cp1, Pt1.x, cp2 * Pt2.x));
            float fc = fmaf(cc0, Pn0.x, fmaf(cc1, Pn1.x, cc2 * Pn2.x));
            r.x = fmaf(wc, fp - fc, fc);
        }
        {
            float fp = fmaf(cp0, Pt0.y, fmaf(cp1, Pt1.y, cp2 * Pt2.y));
            float fc = fmaf(cc0, Pn0.y, fmaf(cc1, Pn1.y, cc2 * Pn2.y));
            r.y = fmaf(wc, fp - fc, fc);
        }
        {
            float fp = fmaf(cp0, Pt0.z, fmaf(cp1, Pt1.z, cp2 * Pt2.z));
            float fc = fmaf(cc0, Pn0.z, fmaf(cc1, Pn1.z, cc2 * Pn2.z));
            r.z = fmaf(wc, fp - fc, fc);
        }
        {
            float fp = fmaf(cp0, Pt0.w, fmaf(cp1, Pt1.w, cp2 * Pt2.w));
            float fc = fmaf(cc0, Pn0.w, fmaf(cc1, Pn1.w, cc2 * Pn2.w));
            r.w = fmaf(wc, fp - fc, fc);
        }

        out4[i] = r;
    }
}

// ---------------- launch ----------------
extern "C" void kernel_launch(void* const* d_in, const int* in_sizes, int n_in,
                              void* d_out, int out_size, void* d_ws, size_t ws_size,
                              hipStream_t stream)
{
    const float* x  = (const float*)d_in[0];
    const float* W1 = (const float*)d_in[1];  const float* b1 = (const float*)d_in[2];
    const float* W2 = (const float*)d_in[3];  const float* b2 = (const float*)d_in[4];
    const float* W3 = (const float*)d_in[5];  const float* b3 = (const float*)d_in[6];
    const float* W4 = (const float*)d_in[7];  const float* b4 = (const float*)d_in[8];
    const float* W5 = (const float*)d_in[9];  const float* b5 = (const float*)d_in[10];
    const float* W6 = (const float*)d_in[11]; const float* b6 = (const float*)d_in[12];

    float* tbl = (float*)d_ws;   // 15 * 28 floats
    const int n = in_sizes[0];

    prep_kernel<<<1, 256, 0, stream>>>(W1, b1, W2, b2, W3, b3, W4, b4, W5, b5, W6, b6, tbl);

    const int blocks = min(NBLK, (n + 255) / 256);
    spline_kernel<<<blocks, 256, 0, stream>>>(x, tbl, (float4*)d_out, n);
}

// Round 3
// 44.934 us; speedup vs baseline: 2.2768x; 2.2768x over previous
//
#include <hip/hip_runtime.h>
#include <math.h>

#define NPTS    18
#define NDIMS   4
#define NITER   15   // num_splines - 1
#define RSTRIDE 28   // floats per table row: 24 used + 4 pad (112 B; random rows <=2-way on banks = free)
#define NBLK    2048

__device__ __forceinline__ float sigm(float v) { return 1.0f / (1.0f + expf(-v)); }
__device__ __forceinline__ float dot4(float4 a, float4 b) {
    return fmaf(a.x, b.x, fmaf(a.y, b.y, fmaf(a.z, b.z, a.w * b.w)));
}

// ---------------- Kernel A: tiny MLP, one block per control point ----------------
// 18 blocks; all heavy reductions split across threads; float4 weight loads.
__global__ __launch_bounds__(256) void mlp_kernel(
    const float* __restrict__ W1, const float* __restrict__ b1,
    const float* __restrict__ W2, const float* __restrict__ b2,
    const float* __restrict__ W3, const float* __restrict__ b3,
    const float* __restrict__ W4, const float* __restrict__ b4,
    const float* __restrict__ W5, const float* __restrict__ b5,
    const float* __restrict__ W6, const float* __restrict__ b6,
    float* __restrict__ P)
{
    __shared__ float h1[16], h2[64], h3[256], h4[64], h5[16], z6[4];
    __shared__ float part[256];
    const int t = threadIdx.x;
    const float pos = (float)(blockIdx.x + 1);

    // L1: (1 -> 16) sigmoid
    if (t < 16) h1[t] = sigm(fmaf(W1[t], pos, b1[t]));
    __syncthreads();

    // L2: (16 -> 64) sigmoid — one thread per output, float4 weights
    if (t < 64) {
        const float4* w = (const float4*)(W2 + t * 16);
        const float4* h = (const float4*)h1;
        float a = b2[t] + ((dot4(w[0], h[0]) + dot4(w[1], h[1])) +
                           (dot4(w[2], h[2]) + dot4(w[3], h[3])));
        h2[t] = sigm(a);
    }
    __syncthreads();

    // L3: (64 -> 256) relu — one thread per output, 4-acc ILP
    {
        const float4* w = (const float4*)(W3 + t * 64);
        const float4* h = (const float4*)h2;
        float a0 = 0.f, a1 = 0.f, a2 = 0.f, a3 = 0.f;
        #pragma unroll
        for (int k = 0; k < 16; k += 4) {
            a0 += dot4(w[k + 0], h[k + 0]);
            a1 += dot4(w[k + 1], h[k + 1]);
            a2 += dot4(w[k + 2], h[k + 2]);
            a3 += dot4(w[k + 3], h[k + 3]);
        }
        h3[t] = fmaxf(b3[t] + ((a0 + a1) + (a2 + a3)), 0.f);
    }
    __syncthreads();

    // L4: (256 -> 64) relu — 4 partial-threads per output (t = q*64 + o)
    {
        const int o = t & 63, q = t >> 6;
        const float4* w = (const float4*)(W4 + o * 256 + q * 64);
        const float4* h = (const float4*)(h3 + q * 64);
        float a0 = 0.f, a1 = 0.f, a2 = 0.f, a3 = 0.f;
        #pragma unroll
        for (int k = 0; k < 16; k += 4) {
            a0 += dot4(w[k + 0], h[k + 0]);
            a1 += dot4(w[k + 1], h[k + 1]);
            a2 += dot4(w[k + 2], h[k + 2]);
            a3 += dot4(w[k + 3], h[k + 3]);
        }
        part[t] = (a0 + a1) + (a2 + a3);
    }
    __syncthreads();
    if (t < 64)
        h4[t] = fmaxf(b4[t] + ((part[t] + part[t + 64]) + (part[t + 128] + part[t + 192])), 0.f);
    __syncthreads();

    // L5: (64 -> 16) relu — 4 partial-threads per output (t = q*16 + o, t < 64)
    if (t < 64) {
        const int o = t & 15, q = t >> 4;
        const float4* w = (const float4*)(W5 + o * 64 + q * 16);
        const float4* h = (const float4*)(h4 + q * 16);
        part[t] = (dot4(w[0], h[0]) + dot4(w[1], h[1])) +
                  (dot4(w[2], h[2]) + dot4(w[3], h[3]));
    }
    __syncthreads();
    if (t < 16)
        h5[t] = fmaxf(b5[t] + ((part[t] + part[t + 16]) + (part[t + 32] + part[t + 48])), 0.f);
    __syncthreads();

    // L6: (16 -> 4) + cumsum over dims
    if (t < 4) {
        const float4* w = (const float4*)(W6 + t * 16);
        const float4* h = (const float4*)h5;
        z6[t] = b6[t] + ((dot4(w[0], h[0]) + dot4(w[1], h[1])) +
                         (dot4(w[2], h[2]) + dot4(w[3], h[3])));
    }
    __syncthreads();
    if (t == 0) {
        float c = 0.f;
        for (int j = 0; j < NDIMS; ++j) {
            c += z6[j];
            P[blockIdx.x * NDIMS + j] = c;
        }
    }
}

// ---------------- Kernel A2: 15-step control-point recurrence -> table ----------------
// row i: [Pt0(4) Pt1(4) Pt2(4) Pn0(4) Pn1(4) Pn2(4) pad(4)]
__global__ void build_table(const float* __restrict__ P, float* __restrict__ tbl)
{
    const int j = threadIdx.x;  // dim 0..3
    if (j >= NDIMS) return;
    float P0 = P[0 * NDIMS + j];
    float P1 = P[1 * NDIMS + j];
    float P2 = P[2 * NDIMS + j];
    for (int i = 0; i < NITER; ++i) {
        float Pnext = P[(3 + i) * NDIMS + j];
        float p0 = (P0 + P2) * 0.25f + P1 * 0.5f;
        float p2 = Pnext;
        float p1 = 2.0f * (P2 - (p0 + p2) * 0.25f);
        float* row = tbl + i * RSTRIDE;
        row[0 * 4 + j] = P0; row[1 * 4 + j] = P1; row[2 * 4 + j] = P2;
        row[3 * 4 + j] = p0; row[4 * 4 + j] = p1; row[5 * 4 + j] = p2;
        P0 = p0; P1 = p1; P2 = p2;
    }
}

// ---------------- Kernel B: per-element spline evaluation (unchanged, ~25 us) ----------------
__global__ __launch_bounds__(256) void spline_kernel(
    const float* __restrict__ x, const float* __restrict__ tbl,
    float4* __restrict__ out4, int n)
{
    __shared__ float s[NITER * RSTRIDE];
    for (int k = threadIdx.x; k < NITER * RSTRIDE; k += 256) s[k] = tbl[k];
    __syncthreads();

    const int stride = NBLK * 256;
    for (int i = blockIdx.x * 256 + threadIdx.x; i < n; i += stride) {
        float u  = x[i] * 15.0f;
        float fi = floorf(u);
        fi = fminf(fmaxf(fi, 0.0f), 14.0f);   // last matching choice == floor bucket
        float d  = (u - fi) * 0.5f;           // in [0, 0.5)

        const float* row = s + (int)fi * RSTRIDE;
        float4 Pt0 = *(const float4*)(row + 0);
        float4 Pt1 = *(const float4*)(row + 4);
        float4 Pt2 = *(const float4*)(row + 8);
        float4 Pn0 = *(const float4*)(row + 12);
        float4 Pn1 = *(const float4*)(row + 16);
        float4 Pn2 = *(const float4*)(row + 20);

        // Bernstein bases: prev at (d+0.5), curr at d
        float dp  = d + 0.5f, omp = 0.5f - d;
        float cp0 = omp * omp, cp1 = 2.0f * dp * omp, cp2 = dp * dp;
        float omd = 1.0f - d;
        float cc0 = omd * omd, cc1 = 2.0f * d * omd, cc2 = d * d;

        // wc = cos^2(pi d) = 0.5 + 0.5*cos(2 pi d); ws = 1 - wc (exact identity)
        float wc = fmaf(0.5f, cospif(2.0f * d), 0.5f);

        float4 r;
        {
            float fp = fmaf(cp0, Pt0.x, fmaf(cp1, Pt1.x, cp2 * Pt2.x));
            float fc = fmaf(cc0, Pn0.x, fmaf(cc1, Pn1.x, cc2 * Pn2.x));
            r.x = fmaf(wc, fp - fc, fc);
        }
        {
            float fp = fmaf(cp0, Pt0.y, fmaf(cp1, Pt1.y, cp2 * Pt2.y));
            float fc = fmaf(cc0, Pn0.y, fmaf(cc1, Pn1.y, cc2 * Pn2.y));
            r.y = fmaf(wc, fp - fc, fc);
        }
        {
            float fp = fmaf(cp0, Pt0.z, fmaf(cp1, Pt1.z, cp2 * Pt2.z));
            float fc = fmaf(cc0, Pn0.z, fmaf(cc1, Pn1.z, cc2 * Pn2.z));
            r.z = fmaf(wc, fp - fc, fc);
        }
        {
            float fp = fmaf(cp0, Pt0.w, fmaf(cp1, Pt1.w, cp2 * Pt2.w));
            float fc = fmaf(cc0, Pn0.w, fmaf(cc1, Pn1.w, cc2 * Pn2.w));
            r.w = fmaf(wc, fp - fc, fc);
        }

        out4[i] = r;
    }
}

// ---------------- launch ----------------
extern "C" void kernel_launch(void* const* d_in, const int* in_sizes, int n_in,
                              void* d_out, int out_size, void* d_ws, size_t ws_size,
                              hipStream_t stream)
{
    const float* x  = (const float*)d_in[0];
    const float* W1 = (const float*)d_in[1];  const float* b1 = (const float*)d_in[2];
    const float* W2 = (const float*)d_in[3];  const float* b2 = (const float*)d_in[4];
    const float* W3 = (const float*)d_in[5];  const float* b3 = (const float*)d_in[6];
    const float* W4 = (const float*)d_in[7];  const float* b4 = (const float*)d_in[8];
    const float* W5 = (const float*)d_in[9];  const float* b5 = (const float*)d_in[10];
    const float* W6 = (const float*)d_in[11]; const float* b6 = (const float*)d_in[12];

    float* P   = (float*)d_ws;        // 72 floats
    float* tbl = (float*)d_ws + 128;  // 15 * 28 floats, 16B-aligned
    const int n = in_sizes[0];

    mlp_kernel<<<NPTS, 256, 0, stream>>>(W1, b1, W2, b2, W3, b3, W4, b4, W5, b5, W6, b6, P);
    build_table<<<1, 64, 0, stream>>>(P, tbl);

    const int blocks = min(NBLK, (n + 255) / 256);
    spline_kernel<<<blocks, 256, 0, stream>>>(x, tbl, (float4*)d_out, n);
}

// Round 4
// 40.980 us; speedup vs baseline: 2.4964x; 1.0965x over previous
//
#include <hip/hip_runtime.h>
#include <math.h>

#define NPTS    18
#define NDIMS   4
#define NITER   15   // num_splines - 1
#define RSTRIDE 28   // floats per table row: 24 used + 4 pad (112 B; random rows <=2-way on banks = free)
#define NBLK    2048

__device__ __forceinline__ float sigm(float v) { return 1.0f / (1.0f + expf(-v)); }
__device__ __forceinline__ float dot4(float4 a, float4 b) {
    return fmaf(a.x, b.x, fmaf(a.y, b.y, fmaf(a.z, b.z, a.w * b.w)));
}

// ---------------- Kernel A: tiny MLP, one block per control point ----------------
// ALL weight loads issued up front (addresses depend only on threadIdx) so the
// 6 dependent layers expose only ONE memory-latency wait instead of six.
__global__ __launch_bounds__(256) void mlp_kernel(
    const float* __restrict__ W1, const float* __restrict__ b1,
    const float* __restrict__ W2, const float* __restrict__ b2,
    const float* __restrict__ W3, const float* __restrict__ b3,
    const float* __restrict__ W4, const float* __restrict__ b4,
    const float* __restrict__ W5, const float* __restrict__ b5,
    const float* __restrict__ W6, const float* __restrict__ b6,
    float* __restrict__ P)
{
    __shared__ float h1[16], h2[64], h3[256], h4[64], h5[16], z6[4];
    __shared__ float part[256];
    const int t = threadIdx.x;
    const float pos = (float)(blockIdx.x + 1);

    // ---- issue all weight loads up front (indices clamped in-bounds for all t) ----
    float w1r = W1[t & 15];
    float b1r = b1[t & 15];

    const int o2 = t & 63;
    float4 w2r[4];
    {
        const float4* v = (const float4*)(W2 + o2 * 16);
        #pragma unroll
        for (int k = 0; k < 4; ++k) w2r[k] = v[k];
    }
    float b2r = b2[o2];

    float4 w3r[16];
    {
        const float4* v = (const float4*)(W3 + t * 64);
        #pragma unroll
        for (int k = 0; k < 16; ++k) w3r[k] = v[k];
    }
    float b3r = b3[t];

    const int o4 = t & 63, q4 = t >> 6;
    float4 w4r[16];
    {
        const float4* v = (const float4*)(W4 + o4 * 256 + q4 * 64);
        #pragma unroll
        for (int k = 0; k < 16; ++k) w4r[k] = v[k];
    }
    float b4r = b4[o4];

    const int o5 = t & 15, q5 = (t >> 4) & 3;
    float4 w5r[4];
    {
        const float4* v = (const float4*)(W5 + o5 * 64 + q5 * 16);
        #pragma unroll
        for (int k = 0; k < 4; ++k) w5r[k] = v[k];
    }
    float b5r = b5[o5];

    const int o6 = t & 3;
    float4 w6r[4];
    {
        const float4* v = (const float4*)(W6 + o6 * 16);
        #pragma unroll
        for (int k = 0; k < 4; ++k) w6r[k] = v[k];
    }
    float b6r = b6[o6];

    // ---- L1: (1 -> 16) sigmoid ----
    if (t < 16) h1[t] = sigm(fmaf(w1r, pos, b1r));
    __syncthreads();

    // ---- L2: (16 -> 64) sigmoid ----
    if (t < 64) {
        const float4* h = (const float4*)h1;
        float a = b2r + ((dot4(w2r[0], h[0]) + dot4(w2r[1], h[1])) +
                         (dot4(w2r[2], h[2]) + dot4(w2r[3], h[3])));
        h2[t] = sigm(a);
    }
    __syncthreads();

    // ---- L3: (64 -> 256) relu — one thread per output, 4-acc ILP ----
    {
        const float4* h = (const float4*)h2;
        float a0 = 0.f, a1 = 0.f, a2 = 0.f, a3 = 0.f;
        #pragma unroll
        for (int k = 0; k < 16; k += 4) {
            a0 += dot4(w3r[k + 0], h[k + 0]);
            a1 += dot4(w3r[k + 1], h[k + 1]);
            a2 += dot4(w3r[k + 2], h[k + 2]);
            a3 += dot4(w3r[k + 3], h[k + 3]);
        }
        h3[t] = fmaxf(b3r + ((a0 + a1) + (a2 + a3)), 0.f);
    }
    __syncthreads();

    // ---- L4: (256 -> 64) relu — 4 partial-threads per output ----
    {
        const float4* h = (const float4*)(h3 + q4 * 64);
        float a0 = 0.f, a1 = 0.f, a2 = 0.f, a3 = 0.f;
        #pragma unroll
        for (int k = 0; k < 16; k += 4) {
            a0 += dot4(w4r[k + 0], h[k + 0]);
            a1 += dot4(w4r[k + 1], h[k + 1]);
            a2 += dot4(w4r[k + 2], h[k + 2]);
            a3 += dot4(w4r[k + 3], h[k + 3]);
        }
        part[t] = (a0 + a1) + (a2 + a3);
    }
    __syncthreads();
    if (t < 64)
        h4[t] = fmaxf(b4r + ((part[t] + part[t + 64]) + (part[t + 128] + part[t + 192])), 0.f);
    __syncthreads();

    // ---- L5: (64 -> 16) relu — 4 partial-threads per output ----
    if (t < 64) {
        const float4* h = (const float4*)(h4 + q5 * 16);
        part[t] = (dot4(w5r[0], h[0]) + dot4(w5r[1], h[1])) +
                  (dot4(w5r[2], h[2]) + dot4(w5r[3], h[3]));
    }
    __syncthreads();
    if (t < 16)
        h5[t] = fmaxf(b5r + ((part[t] + part[t + 16]) + (part[t + 32] + part[t + 48])), 0.f);
    __syncthreads();

    // ---- L6: (16 -> 4) ----
    if (t < 4) {
        const float4* h = (const float4*)h5;
        z6[t] = b6r + ((dot4(w6r[0], h[0]) + dot4(w6r[1], h[1])) +
                       (dot4(w6r[2], h[2]) + dot4(w6r[3], h[3])));
    }
    __syncthreads();

    // ---- cumsum over dims, write P row for this point ----
    if (t < 4) {
        float c = 0.f;
        #pragma unroll
        for (int j = 0; j <= 3; ++j) {
            float v = z6[j];
            if (j <= t) c += v;
        }
        P[blockIdx.x * NDIMS + t] = c;
    }
}

// ---------------- Kernel B: spline evaluation; table built in-block from P ----------------
__global__ __launch_bounds__(256) void spline_kernel(
    const float* __restrict__ x, const float* __restrict__ P,
    float4* __restrict__ out4, int n)
{
    __shared__ float Praw[NPTS * NDIMS];
    __shared__ float s[NITER * RSTRIDE];
    const int t = threadIdx.x;

    if (t < NPTS * NDIMS) Praw[t] = P[t];
    __syncthreads();

    // 15-step control-point recurrence -> LDS table (threads 0..3, ~300 cycles)
    // row i: [Pt0(4) Pt1(4) Pt2(4) Pn0(4) Pn1(4) Pn2(4) pad(4)]
    if (t < NDIMS) {
        const int j = t;
        float P0 = Praw[0 * NDIMS + j];
        float P1 = Praw[1 * NDIMS + j];
        float P2 = Praw[2 * NDIMS + j];
        #pragma unroll
        for (int i = 0; i < NITER; ++i) {
            float Pnext = Praw[(3 + i) * NDIMS + j];
            float p0 = (P0 + P2) * 0.25f + P1 * 0.5f;
            float p2 = Pnext;
            float p1 = 2.0f * (P2 - (p0 + p2) * 0.25f);
            float* row = s + i * RSTRIDE;
            row[0 * 4 + j] = P0; row[1 * 4 + j] = P1; row[2 * 4 + j] = P2;
            row[3 * 4 + j] = p0; row[4 * 4 + j] = p1; row[5 * 4 + j] = p2;
            P0 = p0; P1 = p1; P2 = p2;
        }
    }
    __syncthreads();

    const int stride = NBLK * 256;
    for (int i = blockIdx.x * 256 + t; i < n; i += stride) {
        float u  = x[i] * 15.0f;
        float fi = floorf(u);
        fi = fminf(fmaxf(fi, 0.0f), 14.0f);   // last matching choice == floor bucket
        float d  = (u - fi) * 0.5f;           // in [0, 0.5)

        const float* row = s + (int)fi * RSTRIDE;
        float4 Pt0 = *(const float4*)(row + 0);
        float4 Pt1 = *(const float4*)(row + 4);
        float4 Pt2 = *(const float4*)(row + 8);
        float4 Pn0 = *(const float4*)(row + 12);
        float4 Pn1 = *(const float4*)(row + 16);
        float4 Pn2 = *(const float4*)(row + 20);

        // Bernstein bases: prev at (d+0.5), curr at d
        float dp  = d + 0.5f, omp = 0.5f - d;
        float cp0 = omp * omp, cp1 = 2.0f * dp * omp, cp2 = dp * dp;
        float omd = 1.0f - d;
        float cc0 = omd * omd, cc1 = 2.0f * d * omd, cc2 = d * d;

        // wc = cos^2(pi d) = 0.5 + 0.5*cos(2 pi d); ws = 1 - wc (exact identity)
        float wc = fmaf(0.5f, cospif(2.0f * d), 0.5f);

        float4 r;
        {
            float fp = fmaf(cp0, Pt0.x, fmaf(cp1, Pt1.x, cp2 * Pt2.x));
            float fc = fmaf(cc0, Pn0.x, fmaf(cc1, Pn1.x, cc2 * Pn2.x));
            r.x = fmaf(wc, fp - fc, fc);
        }
        {
            float fp = fmaf(cp0, Pt0.y, fmaf(cp1, Pt1.y, cp2 * Pt2.y));
            float fc = fmaf(cc0, Pn0.y, fmaf(cc1, Pn1.y, cc2 * Pn2.y));
            r.y = fmaf(wc, fp - fc, fc);
        }
        {
            float fp = fmaf(cp0, Pt0.z, fmaf(cp1, Pt1.z, cp2 * Pt2.z));
            float fc = fmaf(cc0, Pn0.z, fmaf(cc1, Pn1.z, cc2 * Pn2.z));
            r.z = fmaf(wc, fp - fc, fc);
        }
        {
            float fp = fmaf(cp0, Pt0.w, fmaf(cp1, Pt1.w, cp2 * Pt2.w));
            float fc = fmaf(cc0, Pn0.w, fmaf(cc1, Pn1.w, cc2 * Pn2.w));
            r.w = fmaf(wc, fp - fc, fc);
        }

        out4[i] = r;
    }
}

// ---------------- launch ----------------
extern "C" void kernel_launch(void* const* d_in, const int* in_sizes, int n_in,
                              void* d_out, int out_size, void* d_ws, size_t ws_size,
                              hipStream_t stream)
{
    const float* x  = (const float*)d_in[0];
    const float* W1 = (const float*)d_in[1];  const float* b1 = (const float*)d_in[2];
    const float* W2 = (const float*)d_in[3];  const float* b2 = (const float*)d_in[4];
    const float* W3 = (const float*)d_in[5];  const float* b3 = (const float*)d_in[6];
    const float* W4 = (const float*)d_in[7];  const float* b4 = (const float*)d_in[8];
    const float* W5 = (const float*)d_in[9];  const float* b5 = (const float*)d_in[10];
    const float* W6 = (const float*)d_in[11]; const float* b6 = (const float*)d_in[12];

    float* P = (float*)d_ws;   // 72 floats
    const int n = in_sizes[0];

    mlp_kernel<<<NPTS, 256, 0, stream>>>(W1, b1, W2, b2, W3, b3, W4, b4, W5, b5, W6, b6, P);

    const int blocks = min(NBLK, (n + 255) / 256);
    spline_kernel<<<blocks, 256, 0, stream>>>(x, P, (float4*)d_out, n);
}